// Round 1
// baseline (6710.781 us; speedup 1.0000x reference)
//
#include <hip/hip_runtime.h>

#define BATCH 128
#define NUSERS 50000

// ---------------- histogram ----------------
__global__ void hist_k(const int* __restrict__ keys, int* __restrict__ hist, int nnz) {
  int i = blockIdx.x * blockDim.x + threadIdx.x;
  int st = gridDim.x * blockDim.x;
  for (; i < nnz; i += st) atomicAdd(&hist[keys[i]], 1);
}

// ---------------- exclusive scan (single block, 1024 threads) ----------------
__global__ void scan_k(const int* __restrict__ hist, int* __restrict__ offs,
                       int* __restrict__ cursor, int n) {
  __shared__ int wsum[16];
  __shared__ int carry;
  int tid = threadIdx.x;
  int lane = tid & 63;
  int wv = tid >> 6;
  if (tid == 0) carry = 0;
  __syncthreads();
  for (int base = 0; base < n; base += 1024) {
    int i = base + tid;
    int x = (i < n) ? hist[i] : 0;
    int incl = x;
#pragma unroll
    for (int d = 1; d < 64; d <<= 1) {
      int y = __shfl_up(incl, (unsigned)d, 64);
      if (lane >= d) incl += y;
    }
    if (lane == 63) wsum[wv] = incl;
    __syncthreads();
    if (wv == 0) {
      int t = (lane < 16) ? wsum[lane] : 0;
#pragma unroll
      for (int d = 1; d < 16; d <<= 1) {
        int y = __shfl_up(t, (unsigned)d, 64);
        if (lane >= d) t += y;
      }
      if (lane < 16) wsum[lane] = t;
    }
    __syncthreads();
    int woff = (wv > 0) ? wsum[wv - 1] : 0;
    int excl = carry + woff + incl - x;
    if (i < n) { offs[i] = excl; cursor[i] = excl; }
    int chunk_total = wsum[15];
    __syncthreads();
    if (tid == 0) carry += chunk_total;
    __syncthreads();
  }
  if (tid == 0) offs[n] = carry;
}

// ---------------- scatter into sorted order ----------------
__global__ void scatter_k(const int* __restrict__ keys, const int* __restrict__ other,
                          const float* __restrict__ vals, int* __restrict__ cursor,
                          int* __restrict__ out_idx, float* __restrict__ out_val, int nnz) {
  int i = blockIdx.x * blockDim.x + threadIdx.x;
  int st = gridDim.x * blockDim.x;
  for (; i < nnz; i += st) {
    int k = keys[i];
    int p = atomicAdd(&cursor[k], 1);
    out_idx[p] = other[i];
    out_val[p] = vals[i];
  }
}

// ---------------- T0 = Xb^T, acc = c0*T0 ----------------
__global__ void transpose_init_k(const float* __restrict__ Xb, const float* __restrict__ coeffs,
                                 float* __restrict__ T0, float* __restrict__ acc, int nitems) {
  __shared__ float tile[32][33];
  int tx = threadIdx.x, ty = threadIdx.y;
  int i0 = blockIdx.x * 32, b0 = blockIdx.y * 32;
#pragma unroll
  for (int j = 0; j < 4; j++) {
    int b = b0 + ty + j * 8;
    tile[ty + j * 8][tx] = Xb[(size_t)b * nitems + i0 + tx];
  }
  __syncthreads();
  float c0 = coeffs[0];
#pragma unroll
  for (int j = 0; j < 4; j++) {
    int il = ty + j * 8;
    float v = tile[tx][il];
    size_t idx = (size_t)(i0 + il) * BATCH + b0 + tx;
    T0[idx] = v;
    acc[idx] = c0 * v;
  }
}

// ---------------- out = acc^T ----------------
__global__ void transpose_out_k(const float* __restrict__ acc, float* __restrict__ out, int nitems) {
  __shared__ float tile[32][33];
  int tx = threadIdx.x, ty = threadIdx.y;
  int i0 = blockIdx.x * 32, b0 = blockIdx.y * 32;
#pragma unroll
  for (int j = 0; j < 4; j++) {
    int il = ty + j * 8;
    tile[il][tx] = acc[(size_t)(i0 + il) * BATCH + b0 + tx];
  }
  __syncthreads();
#pragma unroll
  for (int j = 0; j < 4; j++) {
    int bl = ty + j * 8;
    out[(size_t)(b0 + bl) * nitems + i0 + tx] = tile[tx][bl];
  }
}

// ---------------- phase A: u = X * v  (CSR over users) ----------------
// 32 lanes per row, float4 per lane covers 128 batch cols
__global__ void __launch_bounds__(256) spmm_u_k(const int* __restrict__ offs,
                                                const int* __restrict__ cidx,
                                                const float* __restrict__ cval,
                                                const float* __restrict__ v,
                                                float* __restrict__ u, int nrows) {
  int sub = threadIdx.x >> 5, lane = threadIdx.x & 31;
  int row = blockIdx.x * 8 + sub;
  if (row >= nrows) return;
  int k0 = offs[row], k1 = offs[row + 1];
  float4 acc = make_float4(0.f, 0.f, 0.f, 0.f);
  for (int k = k0; k < k1; ++k) {
    int c = cidx[k];
    float wv = cval[k];
    float4 x = *reinterpret_cast<const float4*>(v + ((size_t)c << 7) + (lane << 2));
    acc.x = fmaf(wv, x.x, acc.x);
    acc.y = fmaf(wv, x.y, acc.y);
    acc.z = fmaf(wv, x.z, acc.z);
    acc.w = fmaf(wv, x.w, acc.w);
  }
  *reinterpret_cast<float4*>(u + ((size_t)row << 7) + (lane << 2)) = acc;
}

// ---------------- phase B: w = X^T * u, fused Chebyshev update ----------------
// t_new = sA * ((w - mid*v)/half) - sB * t_prev ; acc += coeffs[cix] * t_new ; t_prev <- t_new
__global__ void __launch_bounds__(256) spmm_i_cheb_k(const int* __restrict__ offs,
                                                     const int* __restrict__ ridx,
                                                     const float* __restrict__ rval,
                                                     const float* __restrict__ u,
                                                     const float* __restrict__ vcur,
                                                     float* __restrict__ tio,
                                                     float* __restrict__ acc,
                                                     const float* __restrict__ t_mid,
                                                     const float* __restrict__ t_half,
                                                     const float* __restrict__ coeffs,
                                                     int cix, float sA, float sB, int nitems) {
  int sub = threadIdx.x >> 5, lane = threadIdx.x & 31;
  int item = blockIdx.x * 8 + sub;
  if (item >= nitems) return;
  int k0 = offs[item], k1 = offs[item + 1];
  float4 w = make_float4(0.f, 0.f, 0.f, 0.f);
  for (int k = k0; k < k1; ++k) {
    int r = ridx[k];
    float val = rval[k];
    float4 x = *reinterpret_cast<const float4*>(u + ((size_t)r << 7) + (lane << 2));
    w.x = fmaf(val, x.x, w.x);
    w.y = fmaf(val, x.y, w.y);
    w.z = fmaf(val, x.z, w.z);
    w.w = fmaf(val, x.w, w.w);
  }
  float mid = t_mid[0];
  float inv = 1.0f / t_half[0];
  float c = coeffs[cix];
  size_t idx = ((size_t)item << 7) + (lane << 2);
  float4 vv = *reinterpret_cast<const float4*>(vcur + idx);
  float4 t;
  t.x = (w.x - mid * vv.x) * inv;
  t.y = (w.y - mid * vv.y) * inv;
  t.z = (w.z - mid * vv.z) * inv;
  t.w = (w.w - mid * vv.w) * inv;
  if (sB != 0.0f) {
    float4 p = *reinterpret_cast<const float4*>(tio + idx);
    t.x = sA * t.x - sB * p.x;
    t.y = sA * t.y - sB * p.y;
    t.z = sA * t.z - sB * p.z;
    t.w = sA * t.w - sB * p.w;
  }
  *reinterpret_cast<float4*>(tio + idx) = t;
  float4 a = *reinterpret_cast<const float4*>(acc + idx);
  a.x = fmaf(c, t.x, a.x);
  a.y = fmaf(c, t.y, a.y);
  a.z = fmaf(c, t.z, a.z);
  a.w = fmaf(c, t.w, a.w);
  *reinterpret_cast<float4*>(acc + idx) = a;
}

extern "C" void kernel_launch(void* const* d_in, const int* in_sizes, int n_in,
                              void* d_out, int out_size, void* d_ws, size_t ws_size,
                              hipStream_t stream) {
  const float* Xb     = (const float*)d_in[0];
  const float* vals   = (const float*)d_in[1];
  const float* coeffs = (const float*)d_in[2];
  const float* t_mid  = (const float*)d_in[3];
  const float* t_half = (const float*)d_in[4];
  const int*   rows   = (const int*)d_in[5];
  const int*   cols   = (const int*)d_in[6];

  int nnz    = in_sizes[1];
  int nitems = in_sizes[0] / BATCH;   // 20000
  int nusers = NUSERS;                // 50000
  int ncoef  = in_sizes[2];           // 21

  char* base = (char*)d_ws;
  size_t o = 0;
  auto alloc = [&](size_t bytes) -> void* {
    void* p = base + o;
    o = (o + bytes + 255) & ~(size_t)255;
    return p;
  };
  int*   csr_col  = (int*)alloc((size_t)nnz * 4);
  float* csr_val  = (float*)alloc((size_t)nnz * 4);
  int*   csr_offs = (int*)alloc((size_t)(nusers + 1) * 4);
  int*   csc_row  = (int*)alloc((size_t)nnz * 4);
  float* csc_val  = (float*)alloc((size_t)nnz * 4);
  int*   csc_offs = (int*)alloc((size_t)(nitems + 1) * 4);
  int*   cursor   = (int*)alloc((size_t)(nusers + 1) * 4);
  int*   hist     = (int*)alloc((size_t)(nusers + 1) * 4);
  float* u        = (float*)alloc((size_t)nusers * BATCH * 4);
  float* Ta       = (float*)alloc((size_t)nitems * BATCH * 4);
  float* Tb       = (float*)alloc((size_t)nitems * BATCH * 4);
  float* accb     = (float*)alloc((size_t)nitems * BATCH * 4);
  (void)ws_size;

  // build CSR (sorted by user/row)
  hipMemsetAsync(hist, 0, (size_t)(nusers + 1) * 4, stream);
  hist_k<<<2048, 256, 0, stream>>>(rows, hist, nnz);
  scan_k<<<1, 1024, 0, stream>>>(hist, csr_offs, cursor, nusers);
  scatter_k<<<2048, 256, 0, stream>>>(rows, cols, vals, cursor, csr_col, csr_val, nnz);

  // build CSC (sorted by item/col)
  hipMemsetAsync(hist, 0, (size_t)(nusers + 1) * 4, stream);
  hist_k<<<2048, 256, 0, stream>>>(cols, hist, nnz);
  scan_k<<<1, 1024, 0, stream>>>(hist, csc_offs, cursor, nitems);
  scatter_k<<<2048, 256, 0, stream>>>(cols, rows, vals, cursor, csc_row, csc_val, nnz);

  // T0 = Xb^T ; acc = c0*T0
  dim3 tb(32, 8);
  transpose_init_k<<<dim3(nitems / 32, BATCH / 32), tb, 0, stream>>>(Xb, coeffs, Ta, accb, nitems);

  int ublocks = (nusers + 7) / 8;
  int iblocks = (nitems + 7) / 8;

  // s = 1 : T1 = S(T0), acc += c1*T1
  spmm_u_k<<<ublocks, 256, 0, stream>>>(csr_offs, csr_col, csr_val, Ta, u, nusers);
  spmm_i_cheb_k<<<iblocks, 256, 0, stream>>>(csc_offs, csc_row, csc_val, u, Ta, Tb, accb,
                                             t_mid, t_half, coeffs, 1, 1.0f, 0.0f, nitems);
  float* Tp = Ta;  // holds T_{s-2}
  float* Tc = Tb;  // holds T_{s-1}
  for (int s = 2; s < ncoef; ++s) {
    spmm_u_k<<<ublocks, 256, 0, stream>>>(csr_offs, csr_col, csr_val, Tc, u, nusers);
    spmm_i_cheb_k<<<iblocks, 256, 0, stream>>>(csc_offs, csc_row, csc_val, u, Tc, Tp, accb,
                                               t_mid, t_half, coeffs, s, 2.0f, 1.0f, nitems);
    float* tmp = Tp; Tp = Tc; Tc = tmp;
  }

  // out = acc^T
  transpose_out_k<<<dim3(nitems / 32, BATCH / 32), tb, 0, stream>>>(accb, (float*)d_out, nitems);
}

// Round 3
// 5400.419 us; speedup vs baseline: 1.2426x; 1.2426x over previous
//
#include <hip/hip_runtime.h>

#define BATCH 128
#define NUSERS 50000

// ---------------- histogram ----------------
__global__ void hist_k(const int* __restrict__ keys, int* __restrict__ hist, int nnz) {
  int i = blockIdx.x * blockDim.x + threadIdx.x;
  int st = gridDim.x * blockDim.x;
  for (; i < nnz; i += st) atomicAdd(&hist[keys[i]], 1);
}

// ---------------- exclusive scan (single block, 1024 threads) ----------------
__global__ void scan_k(const int* __restrict__ hist, int* __restrict__ offs,
                       int* __restrict__ cursor, int n) {
  __shared__ int wsum[16];
  __shared__ int carry;
  int tid = threadIdx.x;
  int lane = tid & 63;
  int wv = tid >> 6;
  if (tid == 0) carry = 0;
  __syncthreads();
  for (int base = 0; base < n; base += 1024) {
    int i = base + tid;
    int x = (i < n) ? hist[i] : 0;
    int incl = x;
#pragma unroll
    for (int d = 1; d < 64; d <<= 1) {
      int y = __shfl_up(incl, (unsigned)d, 64);
      if (lane >= d) incl += y;
    }
    if (lane == 63) wsum[wv] = incl;
    __syncthreads();
    if (wv == 0) {
      int t = (lane < 16) ? wsum[lane] : 0;
#pragma unroll
      for (int d = 1; d < 16; d <<= 1) {
        int y = __shfl_up(t, (unsigned)d, 64);
        if (lane >= d) t += y;
      }
      if (lane < 16) wsum[lane] = t;
    }
    __syncthreads();
    int woff = (wv > 0) ? wsum[wv - 1] : 0;
    int excl = carry + woff + incl - x;
    if (i < n) { offs[i] = excl; cursor[i] = excl; }
    int chunk_total = wsum[15];
    __syncthreads();
    if (tid == 0) carry += chunk_total;
    __syncthreads();
  }
  if (tid == 0) offs[n] = carry;
}

// ---------------- scatter into sorted order (packed 8B) ----------------
__global__ void scatter_k(const int* __restrict__ keys, const int* __restrict__ other,
                          const float* __restrict__ vals, int* __restrict__ cursor,
                          int2* __restrict__ out_ev, int nnz) {
  int i = blockIdx.x * blockDim.x + threadIdx.x;
  int st = gridDim.x * blockDim.x;
  for (; i < nnz; i += st) {
    int k = keys[i];
    int p = atomicAdd(&cursor[k], 1);
    out_ev[p] = make_int2(other[i], __float_as_int(vals[i]));
  }
}

// ---------------- T0 = Xb^T, acc = c0*T0 ----------------
__global__ void transpose_init_k(const float* __restrict__ Xb, const float* __restrict__ coeffs,
                                 float* __restrict__ T0, float* __restrict__ acc, int nitems) {
  __shared__ float tile[32][33];
  int tx = threadIdx.x, ty = threadIdx.y;
  int i0 = blockIdx.x * 32, b0 = blockIdx.y * 32;
#pragma unroll
  for (int j = 0; j < 4; j++) {
    int b = b0 + ty + j * 8;
    tile[ty + j * 8][tx] = Xb[(size_t)b * nitems + i0 + tx];
  }
  __syncthreads();
  float c0 = coeffs[0];
#pragma unroll
  for (int j = 0; j < 4; j++) {
    int il = ty + j * 8;
    float v = tile[tx][il];
    size_t idx = (size_t)(i0 + il) * BATCH + b0 + tx;
    T0[idx] = v;
    acc[idx] = c0 * v;
  }
}

// ---------------- out = acc^T ----------------
__global__ void transpose_out_k(const float* __restrict__ acc, float* __restrict__ out, int nitems) {
  __shared__ float tile[32][33];
  int tx = threadIdx.x, ty = threadIdx.y;
  int i0 = blockIdx.x * 32, b0 = blockIdx.y * 32;
#pragma unroll
  for (int j = 0; j < 4; j++) {
    int il = ty + j * 8;
    tile[il][tx] = acc[(size_t)(i0 + il) * BATCH + b0 + tx];
  }
  __syncthreads();
#pragma unroll
  for (int j = 0; j < 4; j++) {
    int bl = ty + j * 8;
    out[(size_t)(b0 + bl) * nitems + i0 + tx] = tile[tx][bl];
  }
}

// ---------------- phase A: u = X * v  (CSR over users) ----------------
// one wave (64 lanes) per row, float2 per lane covers 128 batch cols;
// k-unroll x4 => 4 independent 512B gathers in flight per wave
__global__ void __launch_bounds__(256) spmm_u_k(const int* __restrict__ offs,
                                                const int2* __restrict__ ev,
                                                const float* __restrict__ v,
                                                float* __restrict__ u, int nrows) {
  int row = (blockIdx.x << 2) | (threadIdx.x >> 6);
  if (row >= nrows) return;
  int lane = threadIdx.x & 63;
  int k0 = offs[row], k1 = offs[row + 1];
  float2 a0 = {0.f, 0.f}, a1 = {0.f, 0.f}, a2 = {0.f, 0.f}, a3 = {0.f, 0.f};
  int k = k0;
  int co = lane << 1;
  for (; k + 4 <= k1; k += 4) {
    int2 e0 = ev[k], e1 = ev[k + 1], e2 = ev[k + 2], e3 = ev[k + 3];
    float2 x0 = *reinterpret_cast<const float2*>(v + ((size_t)e0.x << 7) + co);
    float2 x1 = *reinterpret_cast<const float2*>(v + ((size_t)e1.x << 7) + co);
    float2 x2 = *reinterpret_cast<const float2*>(v + ((size_t)e2.x << 7) + co);
    float2 x3 = *reinterpret_cast<const float2*>(v + ((size_t)e3.x << 7) + co);
    float w0 = __int_as_float(e0.y), w1 = __int_as_float(e1.y);
    float w2 = __int_as_float(e2.y), w3 = __int_as_float(e3.y);
    a0.x = fmaf(w0, x0.x, a0.x); a0.y = fmaf(w0, x0.y, a0.y);
    a1.x = fmaf(w1, x1.x, a1.x); a1.y = fmaf(w1, x1.y, a1.y);
    a2.x = fmaf(w2, x2.x, a2.x); a2.y = fmaf(w2, x2.y, a2.y);
    a3.x = fmaf(w3, x3.x, a3.x); a3.y = fmaf(w3, x3.y, a3.y);
  }
  for (; k < k1; ++k) {
    int2 e = ev[k];
    float2 x = *reinterpret_cast<const float2*>(v + ((size_t)e.x << 7) + co);
    float w = __int_as_float(e.y);
    a0.x = fmaf(w, x.x, a0.x); a0.y = fmaf(w, x.y, a0.y);
  }
  float2 s;
  s.x = (a0.x + a1.x) + (a2.x + a3.x);
  s.y = (a0.y + a1.y) + (a2.y + a3.y);
  *reinterpret_cast<float2*>(u + ((size_t)row << 7) + co) = s;
}

// ---------------- phase B: w = X^T * u, fused Chebyshev update ----------------
// t_new = sA * ((w - mid*v)/half) - sB * t_prev ; acc += coeffs[cix] * t_new ; t_prev <- t_new
__global__ void __launch_bounds__(256) spmm_i_cheb_k(const int* __restrict__ offs,
                                                     const int2* __restrict__ ev,
                                                     const float* __restrict__ u,
                                                     const float* __restrict__ vcur,
                                                     float* __restrict__ tio,
                                                     float* __restrict__ acc,
                                                     const float* __restrict__ t_mid,
                                                     const float* __restrict__ t_half,
                                                     const float* __restrict__ coeffs,
                                                     int cix, float sA, float sB, int nitems) {
  int item = (blockIdx.x << 2) | (threadIdx.x >> 6);
  if (item >= nitems) return;
  int lane = threadIdx.x & 63;
  int k0 = offs[item], k1 = offs[item + 1];
  float2 a0 = {0.f, 0.f}, a1 = {0.f, 0.f}, a2 = {0.f, 0.f}, a3 = {0.f, 0.f};
  int k = k0;
  int co = lane << 1;
  for (; k + 4 <= k1; k += 4) {
    int2 e0 = ev[k], e1 = ev[k + 1], e2 = ev[k + 2], e3 = ev[k + 3];
    float2 x0 = *reinterpret_cast<const float2*>(u + ((size_t)e0.x << 7) + co);
    float2 x1 = *reinterpret_cast<const float2*>(u + ((size_t)e1.x << 7) + co);
    float2 x2 = *reinterpret_cast<const float2*>(u + ((size_t)e2.x << 7) + co);
    float2 x3 = *reinterpret_cast<const float2*>(u + ((size_t)e3.x << 7) + co);
    float w0 = __int_as_float(e0.y), w1 = __int_as_float(e1.y);
    float w2 = __int_as_float(e2.y), w3 = __int_as_float(e3.y);
    a0.x = fmaf(w0, x0.x, a0.x); a0.y = fmaf(w0, x0.y, a0.y);
    a1.x = fmaf(w1, x1.x, a1.x); a1.y = fmaf(w1, x1.y, a1.y);
    a2.x = fmaf(w2, x2.x, a2.x); a2.y = fmaf(w2, x2.y, a2.y);
    a3.x = fmaf(w3, x3.x, a3.x); a3.y = fmaf(w3, x3.y, a3.y);
  }
  for (; k < k1; ++k) {
    int2 e = ev[k];
    float2 x = *reinterpret_cast<const float2*>(u + ((size_t)e.x << 7) + co);
    float w = __int_as_float(e.y);
    a0.x = fmaf(w, x.x, a0.x); a0.y = fmaf(w, x.y, a0.y);
  }
  float2 w;
  w.x = (a0.x + a1.x) + (a2.x + a3.x);
  w.y = (a0.y + a1.y) + (a2.y + a3.y);

  float mid = t_mid[0];
  float inv = 1.0f / t_half[0];
  float c = coeffs[cix];
  size_t idx = ((size_t)item << 7) + co;
  float2 vv = *reinterpret_cast<const float2*>(vcur + idx);
  float2 t;
  t.x = (w.x - mid * vv.x) * inv;
  t.y = (w.y - mid * vv.y) * inv;
  if (sB != 0.0f) {
    float2 p = *reinterpret_cast<const float2*>(tio + idx);
    t.x = sA * t.x - sB * p.x;
    t.y = sA * t.y - sB * p.y;
  }
  *reinterpret_cast<float2*>(tio + idx) = t;
  float2 a = *reinterpret_cast<const float2*>(acc + idx);
  a.x = fmaf(c, t.x, a.x);
  a.y = fmaf(c, t.y, a.y);
  *reinterpret_cast<float2*>(acc + idx) = a;
}

extern "C" void kernel_launch(void* const* d_in, const int* in_sizes, int n_in,
                              void* d_out, int out_size, void* d_ws, size_t ws_size,
                              hipStream_t stream) {
  const float* Xb     = (const float*)d_in[0];
  const float* vals   = (const float*)d_in[1];
  const float* coeffs = (const float*)d_in[2];
  const float* t_mid  = (const float*)d_in[3];
  const float* t_half = (const float*)d_in[4];
  const int*   rows   = (const int*)d_in[5];
  const int*   cols   = (const int*)d_in[6];

  int nnz    = in_sizes[1];
  int nitems = in_sizes[0] / BATCH;   // 20000
  int nusers = NUSERS;                // 50000
  int ncoef  = in_sizes[2];           // 21

  char* base = (char*)d_ws;
  size_t o = 0;
  auto alloc = [&](size_t bytes) -> void* {
    void* p = base + o;
    o = (o + bytes + 255) & ~(size_t)255;
    return p;
  };
  int2*  csr_ev   = (int2*)alloc((size_t)nnz * 8);
  int*   csr_offs = (int*)alloc((size_t)(nusers + 1) * 4);
  int2*  csc_ev   = (int2*)alloc((size_t)nnz * 8);
  int*   csc_offs = (int*)alloc((size_t)(nitems + 1) * 4);
  int*   cursor   = (int*)alloc((size_t)(nusers + 1) * 4);
  int*   hist     = (int*)alloc((size_t)(nusers + 1) * 4);
  float* u        = (float*)alloc((size_t)nusers * BATCH * 4);
  float* Ta       = (float*)alloc((size_t)nitems * BATCH * 4);
  float* Tb       = (float*)alloc((size_t)nitems * BATCH * 4);
  float* accb     = (float*)alloc((size_t)nitems * BATCH * 4);
  (void)ws_size;

  // build CSR (sorted by user/row)
  hipMemsetAsync(hist, 0, (size_t)(nusers + 1) * 4, stream);
  hist_k<<<2048, 256, 0, stream>>>(rows, hist, nnz);
  scan_k<<<1, 1024, 0, stream>>>(hist, csr_offs, cursor, nusers);
  scatter_k<<<2048, 256, 0, stream>>>(rows, cols, vals, cursor, csr_ev, nnz);

  // build CSC (sorted by item/col)
  hipMemsetAsync(hist, 0, (size_t)(nusers + 1) * 4, stream);
  hist_k<<<2048, 256, 0, stream>>>(cols, hist, nnz);
  scan_k<<<1, 1024, 0, stream>>>(hist, csc_offs, cursor, nitems);
  scatter_k<<<2048, 256, 0, stream>>>(cols, rows, vals, cursor, csc_ev, nnz);

  // T0 = Xb^T ; acc = c0*T0
  dim3 tb(32, 8);
  transpose_init_k<<<dim3(nitems / 32, BATCH / 32), tb, 0, stream>>>(Xb, coeffs, Ta, accb, nitems);

  int ublocks = (nusers + 3) / 4;
  int iblocks = (nitems + 3) / 4;

  // s = 1 : T1 = S(T0), acc += c1*T1
  spmm_u_k<<<ublocks, 256, 0, stream>>>(csr_offs, csr_ev, Ta, u, nusers);
  spmm_i_cheb_k<<<iblocks, 256, 0, stream>>>(csc_offs, csc_ev, u, Ta, Tb, accb,
                                             t_mid, t_half, coeffs, 1, 1.0f, 0.0f, nitems);
  float* Tp = Ta;  // holds T_{s-2}
  float* Tc = Tb;  // holds T_{s-1}
  for (int s = 2; s < ncoef; ++s) {
    spmm_u_k<<<ublocks, 256, 0, stream>>>(csr_offs, csr_ev, Tc, u, nusers);
    spmm_i_cheb_k<<<iblocks, 256, 0, stream>>>(csc_offs, csc_ev, u, Tc, Tp, accb,
                                               t_mid, t_half, coeffs, s, 2.0f, 1.0f, nitems);
    float* tmp = Tp; Tp = Tc; Tc = tmp;
  }

  // out = acc^T
  transpose_out_k<<<dim3(nitems / 32, BATCH / 32), tb, 0, stream>>>(accb, (float*)d_out, nitems);
}

// Round 4
// 5053.804 us; speedup vs baseline: 1.3279x; 1.0686x over previous
//
#include <hip/hip_runtime.h>

#define BATCH 128
#define NUSERS 50000

// ---------------- histogram ----------------
__global__ void hist_k(const int* __restrict__ keys, int* __restrict__ hist, int nnz) {
  int i = blockIdx.x * blockDim.x + threadIdx.x;
  int st = gridDim.x * blockDim.x;
  for (; i < nnz; i += st) atomicAdd(&hist[keys[i]], 1);
}

// ---------------- exclusive scan (single block, 1024 threads) ----------------
__global__ void scan_k(const int* __restrict__ hist, int* __restrict__ offs,
                       int* __restrict__ cursor, int n) {
  __shared__ int wsum[16];
  __shared__ int carry;
  int tid = threadIdx.x;
  int lane = tid & 63;
  int wv = tid >> 6;
  if (tid == 0) carry = 0;
  __syncthreads();
  for (int base = 0; base < n; base += 1024) {
    int i = base + tid;
    int x = (i < n) ? hist[i] : 0;
    int incl = x;
#pragma unroll
    for (int d = 1; d < 64; d <<= 1) {
      int y = __shfl_up(incl, (unsigned)d, 64);
      if (lane >= d) incl += y;
    }
    if (lane == 63) wsum[wv] = incl;
    __syncthreads();
    if (wv == 0) {
      int t = (lane < 16) ? wsum[lane] : 0;
#pragma unroll
      for (int d = 1; d < 16; d <<= 1) {
        int y = __shfl_up(t, (unsigned)d, 64);
        if (lane >= d) t += y;
      }
      if (lane < 16) wsum[lane] = t;
    }
    __syncthreads();
    int woff = (wv > 0) ? wsum[wv - 1] : 0;
    int excl = carry + woff + incl - x;
    if (i < n) { offs[i] = excl; cursor[i] = excl; }
    int chunk_total = wsum[15];
    __syncthreads();
    if (tid == 0) carry += chunk_total;
    __syncthreads();
  }
  if (tid == 0) offs[n] = carry;
}

// ---------------- cursor reinit ----------------
__global__ void reinit_cursor_k(const int* __restrict__ offs, int* __restrict__ cursor, int n) {
  int i = blockIdx.x * blockDim.x + threadIdx.x;
  if (i < n) cursor[i] = offs[i];
}

// ---------------- scatter 1: original COO -> CSC_tmp (key=col), random order ----------------
__global__ void scatter1_k(const int* __restrict__ rows, const int* __restrict__ cols,
                           const float* __restrict__ vals, int* __restrict__ cursor,
                           int2* __restrict__ out_ev, int* __restrict__ keycomp, int nnz) {
  int i = blockIdx.x * blockDim.x + threadIdx.x;
  int st = gridDim.x * blockDim.x;
  for (; i < nnz; i += st) {
    int c = cols[i];
    int p = atomicAdd(&cursor[c], 1);
    out_ev[p] = make_int2(rows[i], __float_as_int(vals[i]));
    keycomp[p] = c;
  }
}

// ---------------- scatter 2/3: re-sort pass. input ev=(destkey-carrying) ----------------
// in_ev[p] = (newkey, val), in_comp[p] = payload index; out_ev[q] = (payload, val), out_comp[q] = newkey
// processing p in (approx) ascending order => payload approx sorted within each newkey bucket
__global__ void rescatter_k(const int2* __restrict__ in_ev, const int* __restrict__ in_comp,
                            int* __restrict__ cursor, int2* __restrict__ out_ev,
                            int* __restrict__ out_comp, int nnz) {
  int i = blockIdx.x * blockDim.x + threadIdx.x;
  int st = gridDim.x * blockDim.x;
  for (; i < nnz; i += st) {
    int2 e = in_ev[i];        // e.x = key for this pass
    int q = atomicAdd(&cursor[e.x], 1);
    out_ev[q] = make_int2(in_comp[i], e.y);
    if (out_comp) out_comp[q] = e.x;
  }
}

// ---------------- T0 = Xb^T, acc = c0*T0 ----------------
__global__ void transpose_init_k(const float* __restrict__ Xb, const float* __restrict__ coeffs,
                                 float* __restrict__ T0, float* __restrict__ acc, int nitems) {
  __shared__ float tile[32][33];
  int tx = threadIdx.x, ty = threadIdx.y;
  int i0 = blockIdx.x * 32, b0 = blockIdx.y * 32;
#pragma unroll
  for (int j = 0; j < 4; j++) {
    int b = b0 + ty + j * 8;
    tile[ty + j * 8][tx] = Xb[(size_t)b * nitems + i0 + tx];
  }
  __syncthreads();
  float c0 = coeffs[0];
#pragma unroll
  for (int j = 0; j < 4; j++) {
    int il = ty + j * 8;
    float v = tile[tx][il];
    size_t idx = (size_t)(i0 + il) * BATCH + b0 + tx;
    T0[idx] = v;
    acc[idx] = c0 * v;
  }
}

// ---------------- out = acc^T ----------------
__global__ void transpose_out_k(const float* __restrict__ acc, float* __restrict__ out, int nitems) {
  __shared__ float tile[32][33];
  int tx = threadIdx.x, ty = threadIdx.y;
  int i0 = blockIdx.x * 32, b0 = blockIdx.y * 32;
#pragma unroll
  for (int j = 0; j < 4; j++) {
    int il = ty + j * 8;
    tile[il][tx] = acc[(size_t)(i0 + il) * BATCH + b0 + tx];
  }
  __syncthreads();
#pragma unroll
  for (int j = 0; j < 4; j++) {
    int bl = ty + j * 8;
    out[(size_t)(b0 + bl) * nitems + i0 + tx] = tile[tx][bl];
  }
}

// ---------------- phase A: u = X * v  (CSR over users) ----------------
// one wave per row; float2/lane = 128 cols; 4-deep gather MLP with ev prefetch pipeline
__global__ void __launch_bounds__(256) spmm_u_k(const int* __restrict__ offs,
                                                const int2* __restrict__ ev,
                                                const float* __restrict__ v,
                                                float* __restrict__ u, int nrows) {
  int wid = __builtin_amdgcn_readfirstlane(threadIdx.x >> 6);
  int row = (blockIdx.x << 2) | wid;
  if (row >= nrows) return;
  int lane = threadIdx.x & 63;
  int co = lane << 1;
  int k0 = offs[row], k1 = offs[row + 1];
  float2 a0 = {0.f, 0.f}, a1 = {0.f, 0.f}, a2 = {0.f, 0.f}, a3 = {0.f, 0.f};
  int k = k0;
  int2 e0, e1, e2, e3;
  bool have = (k + 4 <= k1);
  if (have) { e0 = ev[k]; e1 = ev[k + 1]; e2 = ev[k + 2]; e3 = ev[k + 3]; }
  while (have) {
    float2 x0 = *reinterpret_cast<const float2*>(v + ((size_t)e0.x << 7) + co);
    float2 x1 = *reinterpret_cast<const float2*>(v + ((size_t)e1.x << 7) + co);
    float2 x2 = *reinterpret_cast<const float2*>(v + ((size_t)e2.x << 7) + co);
    float2 x3 = *reinterpret_cast<const float2*>(v + ((size_t)e3.x << 7) + co);
    float w0 = __int_as_float(e0.y), w1 = __int_as_float(e1.y);
    float w2 = __int_as_float(e2.y), w3 = __int_as_float(e3.y);
    k += 4;
    have = (k + 4 <= k1);
    if (have) { e0 = ev[k]; e1 = ev[k + 1]; e2 = ev[k + 2]; e3 = ev[k + 3]; }
    a0.x = fmaf(w0, x0.x, a0.x); a0.y = fmaf(w0, x0.y, a0.y);
    a1.x = fmaf(w1, x1.x, a1.x); a1.y = fmaf(w1, x1.y, a1.y);
    a2.x = fmaf(w2, x2.x, a2.x); a2.y = fmaf(w2, x2.y, a2.y);
    a3.x = fmaf(w3, x3.x, a3.x); a3.y = fmaf(w3, x3.y, a3.y);
  }
  for (; k < k1; ++k) {
    int2 e = ev[k];
    float2 x = *reinterpret_cast<const float2*>(v + ((size_t)e.x << 7) + co);
    float w = __int_as_float(e.y);
    a0.x = fmaf(w, x.x, a0.x); a0.y = fmaf(w, x.y, a0.y);
  }
  float2 s;
  s.x = (a0.x + a1.x) + (a2.x + a3.x);
  s.y = (a0.y + a1.y) + (a2.y + a3.y);
  *reinterpret_cast<float2*>(u + ((size_t)row << 7) + co) = s;
}

// ---------------- phase B: w = X^T * u, fused Chebyshev update ----------------
__global__ void __launch_bounds__(256) spmm_i_cheb_k(const int* __restrict__ offs,
                                                     const int2* __restrict__ ev,
                                                     const float* __restrict__ u,
                                                     const float* __restrict__ vcur,
                                                     float* __restrict__ tio,
                                                     float* __restrict__ acc,
                                                     const float* __restrict__ t_mid,
                                                     const float* __restrict__ t_half,
                                                     const float* __restrict__ coeffs,
                                                     int cix, float sA, float sB, int nitems) {
  int wid = __builtin_amdgcn_readfirstlane(threadIdx.x >> 6);
  int item = (blockIdx.x << 2) | wid;
  if (item >= nitems) return;
  int lane = threadIdx.x & 63;
  int co = lane << 1;
  int k0 = offs[item], k1 = offs[item + 1];
  float2 a0 = {0.f, 0.f}, a1 = {0.f, 0.f}, a2 = {0.f, 0.f}, a3 = {0.f, 0.f};
  int k = k0;
  int2 e0, e1, e2, e3;
  bool have = (k + 4 <= k1);
  if (have) { e0 = ev[k]; e1 = ev[k + 1]; e2 = ev[k + 2]; e3 = ev[k + 3]; }
  while (have) {
    float2 x0 = *reinterpret_cast<const float2*>(u + ((size_t)e0.x << 7) + co);
    float2 x1 = *reinterpret_cast<const float2*>(u + ((size_t)e1.x << 7) + co);
    float2 x2 = *reinterpret_cast<const float2*>(u + ((size_t)e2.x << 7) + co);
    float2 x3 = *reinterpret_cast<const float2*>(u + ((size_t)e3.x << 7) + co);
    float w0 = __int_as_float(e0.y), w1 = __int_as_float(e1.y);
    float w2 = __int_as_float(e2.y), w3 = __int_as_float(e3.y);
    k += 4;
    have = (k + 4 <= k1);
    if (have) { e0 = ev[k]; e1 = ev[k + 1]; e2 = ev[k + 2]; e3 = ev[k + 3]; }
    a0.x = fmaf(w0, x0.x, a0.x); a0.y = fmaf(w0, x0.y, a0.y);
    a1.x = fmaf(w1, x1.x, a1.x); a1.y = fmaf(w1, x1.y, a1.y);
    a2.x = fmaf(w2, x2.x, a2.x); a2.y = fmaf(w2, x2.y, a2.y);
    a3.x = fmaf(w3, x3.x, a3.x); a3.y = fmaf(w3, x3.y, a3.y);
  }
  for (; k < k1; ++k) {
    int2 e = ev[k];
    float2 x = *reinterpret_cast<const float2*>(u + ((size_t)e.x << 7) + co);
    float w = __int_as_float(e.y);
    a0.x = fmaf(w, x.x, a0.x); a0.y = fmaf(w, x.y, a0.y);
  }
  float2 w;
  w.x = (a0.x + a1.x) + (a2.x + a3.x);
  w.y = (a0.y + a1.y) + (a2.y + a3.y);

  float mid = t_mid[0];
  float inv = 1.0f / t_half[0];
  float c = coeffs[cix];
  size_t idx = ((size_t)item << 7) + co;
  float2 vv = *reinterpret_cast<const float2*>(vcur + idx);
  float2 t;
  t.x = (w.x - mid * vv.x) * inv;
  t.y = (w.y - mid * vv.y) * inv;
  if (sB != 0.0f) {
    float2 p = *reinterpret_cast<const float2*>(tio + idx);
    t.x = sA * t.x - sB * p.x;
    t.y = sA * t.y - sB * p.y;
  }
  *reinterpret_cast<float2*>(tio + idx) = t;
  float2 a = *reinterpret_cast<const float2*>(acc + idx);
  a.x = fmaf(c, t.x, a.x);
  a.y = fmaf(c, t.y, a.y);
  *reinterpret_cast<float2*>(acc + idx) = a;
}

extern "C" void kernel_launch(void* const* d_in, const int* in_sizes, int n_in,
                              void* d_out, int out_size, void* d_ws, size_t ws_size,
                              hipStream_t stream) {
  const float* Xb     = (const float*)d_in[0];
  const float* vals   = (const float*)d_in[1];
  const float* coeffs = (const float*)d_in[2];
  const float* t_mid  = (const float*)d_in[3];
  const float* t_half = (const float*)d_in[4];
  const int*   rows   = (const int*)d_in[5];
  const int*   cols   = (const int*)d_in[6];

  int nnz    = in_sizes[1];
  int nitems = in_sizes[0] / BATCH;   // 20000
  int nusers = NUSERS;                // 50000
  int ncoef  = in_sizes[2];           // 21

  char* base = (char*)d_ws;
  size_t o = 0;
  auto alloc = [&](size_t bytes) -> void* {
    void* p = base + o;
    o = (o + bytes + 255) & ~(size_t)255;
    return p;
  };
  // csc_tmp (setup only) aliases csc_ev (iteration): scatter3 writes it last.
  int2*  csc_ev   = (int2*)alloc((size_t)nnz * 8);   // final CSC (rows ~ascending within col)
  int2*  csr_ev   = (int2*)alloc((size_t)nnz * 8);   // final CSR (cols ~ascending within row)
  int*   csr_offs = (int*)alloc((size_t)(nusers + 1) * 4);
  int*   csc_offs = (int*)alloc((size_t)(nitems + 1) * 4);
  int*   cursor   = (int*)alloc((size_t)(nusers + 1) * 4);
  int*   hist     = (int*)alloc((size_t)(nusers + 1) * 4);
  float* u        = (float*)alloc((size_t)nusers * BATCH * 4);
  float* Ta       = (float*)alloc((size_t)nitems * BATCH * 4);
  float* Tb       = (float*)alloc((size_t)nitems * BATCH * 4);
  float* accb     = (float*)alloc((size_t)nitems * BATCH * 4);
  (void)ws_size;
  // setup-only temporaries living in u's space (u untouched until iterations)
  int* comp_a = (int*)u;                       // nnz ints (8 MB)
  int* comp_b = ((int*)u) + nnz;               // nnz ints (8 MB) -- u is 25.6 MB total

  // --- stage 1: COO -> csc_tmp (key=col), random within-col order ---
  hipMemsetAsync(hist, 0, (size_t)(nusers + 1) * 4, stream);
  hist_k<<<2048, 256, 0, stream>>>(cols, hist, nnz);
  scan_k<<<1, 1024, 0, stream>>>(hist, csc_offs, cursor, nitems);
  int2* csc_tmp = csc_ev;  // alias
  scatter1_k<<<2048, 256, 0, stream>>>(rows, cols, vals, cursor, csc_tmp, comp_a, nnz);
  // csc_tmp[p] = (row, val), comp_a[p] = col

  // --- stage 2: csc_tmp -> CSR (key=row); approx ascending col within row ---
  hipMemsetAsync(hist, 0, (size_t)(nusers + 1) * 4, stream);
  hist_k<<<2048, 256, 0, stream>>>(rows, hist, nnz);
  scan_k<<<1, 1024, 0, stream>>>(hist, csr_offs, cursor, nusers);
  rescatter_k<<<2048, 256, 0, stream>>>(csc_tmp, comp_a, cursor, csr_ev, comp_b, nnz);
  // csr_ev[q] = (col, val), comp_b[q] = row

  // --- stage 3: CSR -> CSC (key=col); approx ascending row within col ---
  reinit_cursor_k<<<(nitems + 255) / 256, 256, 0, stream>>>(csc_offs, cursor, nitems);
  // swap ev payload roles: in_ev must be (key=col, val) = csr_ev; comp = row = comp_b
  rescatter_k<<<2048, 256, 0, stream>>>(csr_ev, comp_b, cursor, csc_ev, (int*)nullptr, nnz);
  // csc_ev[p] = (row, val)   (overwrites csc_tmp only after it was consumed in stage 2)

  // T0 = Xb^T ; acc = c0*T0
  dim3 tb(32, 8);
  transpose_init_k<<<dim3(nitems / 32, BATCH / 32), tb, 0, stream>>>(Xb, coeffs, Ta, accb, nitems);

  int ublocks = (nusers + 3) / 4;
  int iblocks = (nitems + 3) / 4;

  // s = 1 : T1 = S(T0), acc += c1*T1
  spmm_u_k<<<ublocks, 256, 0, stream>>>(csr_offs, csr_ev, Ta, u, nusers);
  spmm_i_cheb_k<<<iblocks, 256, 0, stream>>>(csc_offs, csc_ev, u, Ta, Tb, accb,
                                             t_mid, t_half, coeffs, 1, 1.0f, 0.0f, nitems);
  float* Tp = Ta;  // holds T_{s-2}
  float* Tc = Tb;  // holds T_{s-1}
  for (int s = 2; s < ncoef; ++s) {
    spmm_u_k<<<ublocks, 256, 0, stream>>>(csr_offs, csr_ev, Tc, u, nusers);
    spmm_i_cheb_k<<<iblocks, 256, 0, stream>>>(csc_offs, csc_ev, u, Tc, Tp, accb,
                                               t_mid, t_half, coeffs, s, 2.0f, 1.0f, nitems);
    float* tmp = Tp; Tp = Tc; Tc = tmp;
  }

  // out = acc^T
  transpose_out_k<<<dim3(nitems / 32, BATCH / 32), tb, 0, stream>>>(accb, (float*)d_out, nitems);
}